// Round 1
// baseline (2648.277 us; speedup 1.0000x reference)
//
#include <hip/hip_runtime.h>

#define NN 100000
#define NE 3200000
#define HD 64

// ---------------- degree / norm ----------------
__global__ void deg_kernel(const int* __restrict__ dst, int* __restrict__ deg) {
    int e = blockIdx.x * blockDim.x + threadIdx.x;
    if (e < NE) atomicAdd(&deg[dst[e]], 1);
}

__global__ void dinv_kernel(const int* __restrict__ deg, float* __restrict__ dinv) {
    int i = blockIdx.x * blockDim.x + threadIdx.x;
    if (i < NN) dinv[i] = 1.0f / sqrtf((float)(deg[i] + 1)); // +1 self-loop
}

// ---------------- fused modality encoders + GCN layer-0 matmul ----------------
// h[n][c] = sum_k concat(relu(enc))[n][k] * W0[k][c]
__global__ void __launch_bounds__(256) encmm0_kernel(
    const float* __restrict__ xf, const float* __restrict__ xw, const float* __restrict__ xt,
    const float* __restrict__ Wf, const float* __restrict__ bf,
    const float* __restrict__ Ww, const float* __restrict__ bw,
    const float* __restrict__ Wt, const float* __restrict__ bt,
    const float* __restrict__ W0, float* __restrict__ h) {
    __shared__ float xs[4][192];
    int t = threadIdx.x;
    int n0 = blockIdx.x * 4;
    for (int j = t; j < 4 * 192; j += 256) {
        int nl = j / 192, col = j - nl * 192;
        int n = n0 + nl;
        float v = 0.f;
        if (n < NN) {
            float acc;
            if (col < 64) {
                acc = bf[col];
                #pragma unroll
                for (int k = 0; k < 8; k++) acc = fmaf(xf[n * 8 + k], Wf[k * 64 + col], acc);
            } else if (col < 128) {
                int c = col - 64;
                acc = bw[c];
                #pragma unroll
                for (int k = 0; k < 12; k++) acc = fmaf(xw[n * 12 + k], Ww[k * 64 + c], acc);
            } else {
                int c = col - 128;
                acc = bt[c];
                #pragma unroll
                for (int k = 0; k < 10; k++) acc = fmaf(xt[n * 10 + k], Wt[k * 64 + c], acc);
            }
            v = fmaxf(acc, 0.f);
        }
        xs[nl][col] = v;
    }
    __syncthreads();
    int nl = t >> 6, c = t & 63;
    int n = n0 + nl;
    float acc = 0.f;
    #pragma unroll
    for (int k = 0; k < 192; k++) acc = fmaf(xs[nl][k], W0[k * 64 + c], acc);
    if (n < NN) h[n * 64 + c] = acc;
}

// ---------------- plain 64x64 matmul: h = x @ W ----------------
__global__ void __launch_bounds__(256) mm64_kernel(
    const float* __restrict__ x, const float* __restrict__ W, float* __restrict__ h) {
    __shared__ float xs[4][64];
    int t = threadIdx.x;
    int n0 = blockIdx.x * 4;
    int nl = t >> 6, c = t & 63;
    int n = n0 + nl;
    xs[nl][c] = (n < NN) ? x[n * 64 + c] : 0.f;
    __syncthreads();
    float acc = 0.f;
    #pragma unroll
    for (int k = 0; k < 64; k++) acc = fmaf(xs[nl][k], W[k * 64 + c], acc);
    if (n < NN) h[n * 64 + c] = acc;
}

// ---------------- edge scatter: agg[dst] += h[src] * dinv[src]*dinv[dst] ----------------
// one wave (64 lanes) per edge; lane = feature index
__global__ void __launch_bounds__(256) scatter_kernel(
    const int* __restrict__ src, const int* __restrict__ dst,
    const float* __restrict__ dinv, const float* __restrict__ h,
    float* __restrict__ agg) {
    int gtid = blockIdx.x * blockDim.x + threadIdx.x;
    int wid = gtid >> 6;
    int lane = threadIdx.x & 63;
    int nw = (gridDim.x * blockDim.x) >> 6;
    for (int e = wid; e < NE; e += nw) {
        int s = src[e], d = dst[e];
        float nrm = dinv[s] * dinv[d];
        atomicAdd(&agg[d * 64 + lane], h[s * 64 + lane] * nrm);
    }
}

// ---------------- finalize (in-place into agg): relu(agg + h*dinv^2 + b) ----------------
__global__ void finalize_kernel(
    float* __restrict__ agg, const float* __restrict__ h,
    const float* __restrict__ dinv, const float* __restrict__ b) {
    int i = blockIdx.x * blockDim.x + threadIdx.x;
    if (i < NN * 64) {
        int n = i >> 6, c = i & 63;
        float di = dinv[n];
        float v = agg[i] + h[i] * di * di + b[c];
        agg[i] = fmaxf(v, 0.f);
    }
}

// ---------------- fused output MLP: out = relu(x@w1 + b1) @ w2 + b2 ----------------
// 8 nodes per 256-thread block; 32 lanes per node (one per hidden unit)
__global__ void __launch_bounds__(256) mlp_kernel(
    const float* __restrict__ x, const float* __restrict__ w1, const float* __restrict__ b1,
    const float* __restrict__ w2, const float* __restrict__ b2, float* __restrict__ out) {
    int t = threadIdx.x;
    int nl = t >> 5, j = t & 31;
    int n = blockIdx.x * 8 + nl;
    float acc = b1[j];
    if (n < NN) {
        #pragma unroll
        for (int k = 0; k < 64; k++) acc = fmaf(x[n * 64 + k], w1[k * 32 + j], acc);
    }
    float hj = fmaxf(acc, 0.f) * w2[j];
    #pragma unroll
    for (int off = 16; off; off >>= 1) hj += __shfl_down(hj, off, 32);
    if (j == 0 && n < NN) out[n] = hj + b2[0];
}

extern "C" void kernel_launch(void* const* d_in, const int* in_sizes, int n_in,
                              void* d_out, int out_size, void* d_ws, size_t ws_size,
                              hipStream_t stream) {
    const float* xf = (const float*)d_in[0];
    const float* xw = (const float*)d_in[1];
    const float* xt = (const float*)d_in[2];
    const int*   ei = (const int*)d_in[3];
    const int*   src = ei;
    const int*   dst = ei + NE;
    const float* Wf = (const float*)d_in[4];
    const float* bf = (const float*)d_in[5];
    const float* Ww = (const float*)d_in[6];
    const float* bw = (const float*)d_in[7];
    const float* Wt = (const float*)d_in[8];
    const float* bt = (const float*)d_in[9];
    const float* W0 = (const float*)d_in[10];
    const float* b0 = (const float*)d_in[11];
    const float* W1 = (const float*)d_in[12];
    const float* b1 = (const float*)d_in[13];
    const float* W2 = (const float*)d_in[14];
    const float* b2 = (const float*)d_in[15];
    const float* ow1 = (const float*)d_in[16];
    const float* ob1 = (const float*)d_in[17];
    const float* ow2 = (const float*)d_in[18];
    const float* ob2 = (const float*)d_in[19];
    float* out = (float*)d_out;

    // workspace layout (needs ~52.2 MB)
    char* w = (char*)d_ws;
    float* h    = (float*)w;  w += (size_t)NN * 64 * 4;   // pre-agg features
    float* agg  = (float*)w;  w += (size_t)NN * 64 * 4;   // aggregate / layer output (in-place)
    float* dinv = (float*)w;  w += (size_t)NN * 4;
    int*   deg  = (int*)w;    w += (size_t)NN * 4;

    // degree + norm (once; shared by all 3 layers)
    hipMemsetAsync(deg, 0, (size_t)NN * 4, stream);
    deg_kernel<<<(NE + 255) / 256, 256, 0, stream>>>(dst, deg);
    dinv_kernel<<<(NN + 255) / 256, 256, 0, stream>>>(deg, dinv);

    // ---- layer 0: fused encoders + matmul ----
    encmm0_kernel<<<(NN + 3) / 4, 256, 0, stream>>>(xf, xw, xt, Wf, bf, Ww, bw, Wt, bt, W0, h);
    hipMemsetAsync(agg, 0, (size_t)NN * 64 * 4, stream);
    scatter_kernel<<<2048, 256, 0, stream>>>(src, dst, dinv, h, agg);
    finalize_kernel<<<(NN * 64 + 255) / 256, 256, 0, stream>>>(agg, h, dinv, b0);

    // ---- layer 1 ----
    mm64_kernel<<<(NN + 3) / 4, 256, 0, stream>>>(agg, W1, h);
    hipMemsetAsync(agg, 0, (size_t)NN * 64 * 4, stream);
    scatter_kernel<<<2048, 256, 0, stream>>>(src, dst, dinv, h, agg);
    finalize_kernel<<<(NN * 64 + 255) / 256, 256, 0, stream>>>(agg, h, dinv, b1);

    // ---- layer 2 ----
    mm64_kernel<<<(NN + 3) / 4, 256, 0, stream>>>(agg, W2, h);
    hipMemsetAsync(agg, 0, (size_t)NN * 64 * 4, stream);
    scatter_kernel<<<2048, 256, 0, stream>>>(src, dst, dinv, h, agg);
    finalize_kernel<<<(NN * 64 + 255) / 256, 256, 0, stream>>>(agg, h, dinv, b2);

    // ---- output MLP ----
    mlp_kernel<<<(NN + 7) / 8, 256, 0, stream>>>(agg, ow1, ob1, ow2, ob2, out);
}

// Round 2
// 1046.332 us; speedup vs baseline: 2.5310x; 2.5310x over previous
//
#include <hip/hip_runtime.h>

#define NN 100000
#define NE 3200000
#define HD 64
#define SCAN_CHUNK 1024
#define NBLK ((NN + SCAN_CHUNK - 1) / SCAN_CHUNK)   // 98

// ---------------- degree histogram ----------------
__global__ void deg_kernel(const int* __restrict__ dst, int* __restrict__ deg) {
    int e = blockIdx.x * blockDim.x + threadIdx.x;
    if (e < NE) atomicAdd(&deg[dst[e]], 1);
}

__global__ void dinv_kernel(const int* __restrict__ deg, float* __restrict__ dinv) {
    int i = blockIdx.x * blockDim.x + threadIdx.x;
    if (i < NN) dinv[i] = 1.0f / sqrtf((float)(deg[i] + 1)); // +1 self-loop
}

// ---------------- prefix scan (3 kernels) ----------------
__global__ void block_sum_kernel(const int* __restrict__ deg, int* __restrict__ bsum) {
    __shared__ int red[256];
    int b = blockIdx.x, t = threadIdx.x;
    int base = b * SCAN_CHUNK + t * 4;
    int s = 0;
    #pragma unroll
    for (int i = 0; i < 4; i++) { int g = base + i; if (g < NN) s += deg[g]; }
    red[t] = s; __syncthreads();
    for (int off = 128; off > 0; off >>= 1) {
        if (t < off) red[t] += red[t + off];
        __syncthreads();
    }
    if (t == 0) bsum[b] = red[0];
}

__global__ void scan_bsum_kernel(const int* __restrict__ bsum, int* __restrict__ boff,
                                 int* __restrict__ rowptr) {
    if (threadIdx.x == 0) {
        int off = 0;
        for (int i = 0; i < NBLK; i++) { boff[i] = off; off += bsum[i]; }
        rowptr[NN] = off;   // == NE
    }
}

__global__ void scan_fill_kernel(const int* __restrict__ deg, const int* __restrict__ boff,
                                 int* __restrict__ rowptr) {
    __shared__ int part[256];
    int b = blockIdx.x, t = threadIdx.x;
    int base = b * SCAN_CHUNK + t * 4;
    int v[4];
    #pragma unroll
    for (int i = 0; i < 4; i++) { int g = base + i; v[i] = (g < NN) ? deg[g] : 0; }
    int tsum = v[0] + v[1] + v[2] + v[3];
    part[t] = tsum; __syncthreads();
    // Hillis-Steele inclusive scan over 256 thread-sums
    for (int off = 1; off < 256; off <<= 1) {
        int x = (t >= off) ? part[t - off] : 0;
        __syncthreads();
        part[t] += x;
        __syncthreads();
    }
    int o = boff[b] + part[t] - tsum;   // exclusive prefix for this thread
    #pragma unroll
    for (int i = 0; i < 4; i++) {
        int g = base + i;
        if (g < NN) rowptr[g] = o;
        o += v[i];
    }
}

// ---------------- CSR fill: colw[idx] = {src, dinv[src]} ----------------
__global__ void fill_csr_kernel(const int* __restrict__ src, const int* __restrict__ dst,
                                const int* __restrict__ rowptr, int* __restrict__ cursor,
                                const float* __restrict__ dinv, int2* __restrict__ colw) {
    int e = blockIdx.x * blockDim.x + threadIdx.x;
    if (e < NE) {
        int s = src[e], d = dst[e];
        int slot = atomicAdd(&cursor[d], 1);
        int2 p;
        p.x = s;
        p.y = __float_as_int(dinv[s]);
        colw[rowptr[d] + slot] = p;
    }
}

// ---------------- fused modality encoders + GCN layer-0 matmul ----------------
__global__ void __launch_bounds__(256) encmm0_kernel(
    const float* __restrict__ xf, const float* __restrict__ xw, const float* __restrict__ xt,
    const float* __restrict__ Wf, const float* __restrict__ bf,
    const float* __restrict__ Ww, const float* __restrict__ bw,
    const float* __restrict__ Wt, const float* __restrict__ bt,
    const float* __restrict__ W0, float* __restrict__ h) {
    __shared__ float xs[4][192];
    int t = threadIdx.x;
    int n0 = blockIdx.x * 4;
    for (int j = t; j < 4 * 192; j += 256) {
        int nl = j / 192, col = j - nl * 192;
        int n = n0 + nl;
        float v = 0.f;
        if (n < NN) {
            float acc;
            if (col < 64) {
                acc = bf[col];
                #pragma unroll
                for (int k = 0; k < 8; k++) acc = fmaf(xf[n * 8 + k], Wf[k * 64 + col], acc);
            } else if (col < 128) {
                int c = col - 64;
                acc = bw[c];
                #pragma unroll
                for (int k = 0; k < 12; k++) acc = fmaf(xw[n * 12 + k], Ww[k * 64 + c], acc);
            } else {
                int c = col - 128;
                acc = bt[c];
                #pragma unroll
                for (int k = 0; k < 10; k++) acc = fmaf(xt[n * 10 + k], Wt[k * 64 + c], acc);
            }
            v = fmaxf(acc, 0.f);
        }
        xs[nl][col] = v;
    }
    __syncthreads();
    int nl = t >> 6, c = t & 63;
    int n = n0 + nl;
    float acc = 0.f;
    #pragma unroll
    for (int k = 0; k < 192; k++) acc = fmaf(xs[nl][k], W0[k * 64 + c], acc);
    if (n < NN) h[n * 64 + c] = acc;
}

// ---------------- plain 64x64 matmul: h = x @ W ----------------
__global__ void __launch_bounds__(256) mm64_kernel(
    const float* __restrict__ x, const float* __restrict__ W, float* __restrict__ h) {
    __shared__ float xs[4][64];
    int t = threadIdx.x;
    int n0 = blockIdx.x * 4;
    int nl = t >> 6, c = t & 63;
    int n = n0 + nl;
    xs[nl][c] = (n < NN) ? x[n * 64 + c] : 0.f;
    __syncthreads();
    float acc = 0.f;
    #pragma unroll
    for (int k = 0; k < 64; k++) acc = fmaf(xs[nl][k], W[k * 64 + c], acc);
    if (n < NN) h[n * 64 + c] = acc;
}

// ---------------- CSR gather + finalize: out = relu(dinv[n]*(sum + h[n]*dinv[n]) + b) ----------------
// one wave per node, lane = feature index
__global__ void __launch_bounds__(256) gather_kernel(
    const int2* __restrict__ colw, const int* __restrict__ rowptr,
    const float* __restrict__ dinv, const float* __restrict__ h,
    const float* __restrict__ bias, float* __restrict__ out) {
    int n = (blockIdx.x * blockDim.x + threadIdx.x) >> 6;
    int lane = threadIdx.x & 63;
    if (n >= NN) return;
    int r0 = rowptr[n], r1 = rowptr[n + 1];
    float acc = 0.f;
    for (int base = r0; base < r1; base += 64) {
        int cnt = min(64, r1 - base);
        int2 p = make_int2(0, 0);
        if (lane < cnt) p = colw[base + lane];   // coalesced: 64 edges per load
        int j = 0;
        for (; j + 4 <= cnt; j += 4) {
            int   s0 = __shfl(p.x, j + 0); float w0 = __int_as_float(__shfl(p.y, j + 0));
            int   s1 = __shfl(p.x, j + 1); float w1 = __int_as_float(__shfl(p.y, j + 1));
            int   s2 = __shfl(p.x, j + 2); float w2 = __int_as_float(__shfl(p.y, j + 2));
            int   s3 = __shfl(p.x, j + 3); float w3 = __int_as_float(__shfl(p.y, j + 3));
            float v0 = h[(size_t)s0 * 64 + lane];
            float v1 = h[(size_t)s1 * 64 + lane];
            float v2 = h[(size_t)s2 * 64 + lane];
            float v3 = h[(size_t)s3 * 64 + lane];
            acc = fmaf(v0, w0, acc);
            acc = fmaf(v1, w1, acc);
            acc = fmaf(v2, w2, acc);
            acc = fmaf(v3, w3, acc);
        }
        for (; j < cnt; j++) {
            int s = __shfl(p.x, j);
            float w = __int_as_float(__shfl(p.y, j));
            acc = fmaf(h[(size_t)s * 64 + lane], w, acc);
        }
    }
    float dn = dinv[n];
    float v = dn * (acc + h[(size_t)n * 64 + lane] * dn) + bias[lane];
    out[(size_t)n * 64 + lane] = fmaxf(v, 0.f);
}

// ---------------- fused output MLP ----------------
__global__ void __launch_bounds__(256) mlp_kernel(
    const float* __restrict__ x, const float* __restrict__ w1, const float* __restrict__ b1,
    const float* __restrict__ w2, const float* __restrict__ b2, float* __restrict__ out) {
    int t = threadIdx.x;
    int nl = t >> 5, j = t & 31;
    int n = blockIdx.x * 8 + nl;
    float acc = b1[j];
    if (n < NN) {
        #pragma unroll
        for (int k = 0; k < 64; k++) acc = fmaf(x[n * 64 + k], w1[k * 32 + j], acc);
    }
    float hj = fmaxf(acc, 0.f) * w2[j];
    #pragma unroll
    for (int off = 16; off; off >>= 1) hj += __shfl_down(hj, off, 32);
    if (j == 0 && n < NN) out[n] = hj + b2[0];
}

extern "C" void kernel_launch(void* const* d_in, const int* in_sizes, int n_in,
                              void* d_out, int out_size, void* d_ws, size_t ws_size,
                              hipStream_t stream) {
    const float* xf = (const float*)d_in[0];
    const float* xw = (const float*)d_in[1];
    const float* xt = (const float*)d_in[2];
    const int*   ei = (const int*)d_in[3];
    const int*   src = ei;
    const int*   dst = ei + NE;
    const float* Wf = (const float*)d_in[4];
    const float* bf = (const float*)d_in[5];
    const float* Ww = (const float*)d_in[6];
    const float* bw = (const float*)d_in[7];
    const float* Wt = (const float*)d_in[8];
    const float* bt = (const float*)d_in[9];
    const float* W0 = (const float*)d_in[10];
    const float* b0 = (const float*)d_in[11];
    const float* W1 = (const float*)d_in[12];
    const float* b1 = (const float*)d_in[13];
    const float* W2 = (const float*)d_in[14];
    const float* b2 = (const float*)d_in[15];
    const float* ow1 = (const float*)d_in[16];
    const float* ob1 = (const float*)d_in[17];
    const float* ow2 = (const float*)d_in[18];
    const float* ob2 = (const float*)d_in[19];
    float* out = (float*)d_out;

    // workspace layout (~104 MB)
    char* w = (char*)d_ws;
    float* h      = (float*)w;  w += (size_t)NN * 64 * 4;    // 25.6 MB
    float* agg    = (float*)w;  w += (size_t)NN * 64 * 4;    // 25.6 MB
    int2*  colw   = (int2*)w;   w += (size_t)NE * 8;         // 25.6 MB
    float* dinv   = (float*)w;  w += (size_t)NN * 4;
    int*   deg    = (int*)w;    w += (size_t)NN * 4;
    int*   cursor = (int*)w;    w += (size_t)NN * 4;
    int*   rowptr = (int*)w;    w += (size_t)(NN + 1) * 4;
    int*   bsum   = (int*)w;    w += (size_t)NBLK * 4;
    int*   boff   = (int*)w;    w += (size_t)NBLK * 4;

    // ---- CSR build (once; reused by all 3 layers) ----
    hipMemsetAsync(deg, 0, (size_t)NN * 4, stream);
    hipMemsetAsync(cursor, 0, (size_t)NN * 4, stream);
    deg_kernel<<<(NE + 255) / 256, 256, 0, stream>>>(dst, deg);
    dinv_kernel<<<(NN + 255) / 256, 256, 0, stream>>>(deg, dinv);
    block_sum_kernel<<<NBLK, 256, 0, stream>>>(deg, bsum);
    scan_bsum_kernel<<<1, 64, 0, stream>>>(bsum, boff, rowptr);
    scan_fill_kernel<<<NBLK, 256, 0, stream>>>(deg, boff, rowptr);
    fill_csr_kernel<<<(NE + 255) / 256, 256, 0, stream>>>(src, dst, rowptr, cursor, dinv, colw);

    // ---- layer 0: fused encoders + matmul, then gather+finalize ----
    encmm0_kernel<<<(NN + 3) / 4, 256, 0, stream>>>(xf, xw, xt, Wf, bf, Ww, bw, Wt, bt, W0, h);
    gather_kernel<<<(NN * 64 + 255) / 256, 256, 0, stream>>>(colw, rowptr, dinv, h, b0, agg);

    // ---- layer 1 ----
    mm64_kernel<<<(NN + 3) / 4, 256, 0, stream>>>(agg, W1, h);
    gather_kernel<<<(NN * 64 + 255) / 256, 256, 0, stream>>>(colw, rowptr, dinv, h, b1, agg);

    // ---- layer 2 ----
    mm64_kernel<<<(NN + 3) / 4, 256, 0, stream>>>(agg, W2, h);
    gather_kernel<<<(NN * 64 + 255) / 256, 256, 0, stream>>>(colw, rowptr, dinv, h, b2, agg);

    // ---- output MLP ----
    mlp_kernel<<<(NN + 7) / 8, 256, 0, stream>>>(agg, ow1, ob1, ow2, ob2, out);
}

// Round 3
// 930.119 us; speedup vs baseline: 2.8472x; 1.1249x over previous
//
#include <hip/hip_runtime.h>

#define NN 100000
#define NE 3200000
#define HD 64
#define SCAN_CHUNK 1024
#define NBLK ((NN + SCAN_CHUNK - 1) / SCAN_CHUNK)   // 98

__device__ __forceinline__ void fma4(float4& a, float s, const float4& b) {
    a.x = fmaf(s, b.x, a.x); a.y = fmaf(s, b.y, a.y);
    a.z = fmaf(s, b.z, a.z); a.w = fmaf(s, b.w, a.w);
}

// ---------------- degree histogram ----------------
__global__ void deg_kernel(const int* __restrict__ dst, int* __restrict__ deg) {
    int e = blockIdx.x * blockDim.x + threadIdx.x;
    if (e < NE) atomicAdd(&deg[dst[e]], 1);
}

__global__ void dinv_kernel(const int* __restrict__ deg, float* __restrict__ dinv) {
    int i = blockIdx.x * blockDim.x + threadIdx.x;
    if (i < NN) dinv[i] = 1.0f / sqrtf((float)(deg[i] + 1)); // +1 self-loop
}

// ---------------- prefix scan (3 kernels) ----------------
__global__ void block_sum_kernel(const int* __restrict__ deg, int* __restrict__ bsum) {
    __shared__ int red[256];
    int b = blockIdx.x, t = threadIdx.x;
    int base = b * SCAN_CHUNK + t * 4;
    int s = 0;
    #pragma unroll
    for (int i = 0; i < 4; i++) { int g = base + i; if (g < NN) s += deg[g]; }
    red[t] = s; __syncthreads();
    for (int off = 128; off > 0; off >>= 1) {
        if (t < off) red[t] += red[t + off];
        __syncthreads();
    }
    if (t == 0) bsum[b] = red[0];
}

__global__ void scan_bsum_kernel(const int* __restrict__ bsum, int* __restrict__ boff,
                                 int* __restrict__ rowptr) {
    if (threadIdx.x == 0) {
        int off = 0;
        for (int i = 0; i < NBLK; i++) { boff[i] = off; off += bsum[i]; }
        rowptr[NN] = off;   // == NE
    }
}

__global__ void scan_fill_kernel(const int* __restrict__ deg, const int* __restrict__ boff,
                                 int* __restrict__ rowptr) {
    __shared__ int part[256];
    int b = blockIdx.x, t = threadIdx.x;
    int base = b * SCAN_CHUNK + t * 4;
    int v[4];
    #pragma unroll
    for (int i = 0; i < 4; i++) { int g = base + i; v[i] = (g < NN) ? deg[g] : 0; }
    int tsum = v[0] + v[1] + v[2] + v[3];
    part[t] = tsum; __syncthreads();
    for (int off = 1; off < 256; off <<= 1) {
        int x = (t >= off) ? part[t - off] : 0;
        __syncthreads();
        part[t] += x;
        __syncthreads();
    }
    int o = boff[b] + part[t] - tsum;   // exclusive prefix for this thread
    #pragma unroll
    for (int i = 0; i < 4; i++) {
        int g = base + i;
        if (g < NN) rowptr[g] = o;
        o += v[i];
    }
}

// ---------------- CSR fill: colw[idx] = {src, dinv[src]} ----------------
__global__ void fill_csr_kernel(const int* __restrict__ src, const int* __restrict__ dst,
                                const int* __restrict__ rowptr, int* __restrict__ cursor,
                                const float* __restrict__ dinv, int2* __restrict__ colw) {
    int e = blockIdx.x * blockDim.x + threadIdx.x;
    if (e < NE) {
        int s = src[e], d = dst[e];
        int slot = atomicAdd(&cursor[d], 1);
        int2 p;
        p.x = s;
        p.y = __float_as_int(dinv[s]);
        colw[rowptr[d] + slot] = p;
    }
}

// ---------------- fused modality encoders + GCN layer-0 matmul ----------------
// 64-node tile, K=192 split in two 96-halves. Register-blocked 4x4 per thread.
__global__ void __launch_bounds__(256) encmm0_kernel(
    const float* __restrict__ xf, const float* __restrict__ xw, const float* __restrict__ xt,
    const float* __restrict__ Wf, const float* __restrict__ bf,
    const float* __restrict__ Ww, const float* __restrict__ bw,
    const float* __restrict__ Wt, const float* __restrict__ bt,
    const float* __restrict__ W0, float* __restrict__ h) {
    __shared__ float xin[64][32];    // fire[0..7], wea[8..19], ter[20..29]
    __shared__ float xs[64][100];    // encoder outputs for current 96-half (+4 pad)
    __shared__ float ws[96][64];     // W0 rows for current half
    int t = threadIdx.x;
    int n0 = blockIdx.x * 64;

    // ---- stage raw inputs ----
    {
        const float4* xf4 = (const float4*)xf;
        for (int i = t; i < 128; i += 256) {             // 64 nodes x 2 float4
            int n = i >> 1, q = i & 1;
            int gn = n0 + n;
            float4 v = make_float4(0, 0, 0, 0);
            if (gn < NN) v = xf4[(size_t)gn * 2 + q];
            *(float4*)&xin[n][q * 4] = v;
        }
        const float4* xw4 = (const float4*)xw;
        for (int i = t; i < 192; i += 256) {             // 64 nodes x 3 float4
            int n = i / 3, q = i - n * 3;
            int gn = n0 + n;
            float4 v = make_float4(0, 0, 0, 0);
            if (gn < NN) v = xw4[(size_t)gn * 3 + q];
            *(float4*)&xin[n][8 + q * 4] = v;
        }
        const float2* xt2 = (const float2*)xt;
        for (int i = t; i < 320; i += 256) {             // 64 nodes x 5 float2
            int n = i / 5, q = i - n * 5;
            int gn = n0 + n;
            float2 v = make_float2(0, 0);
            if (gn < NN) v = xt2[(size_t)gn * 5 + q];
            *(float2*)&xin[n][20 + q * 2] = v;
        }
    }

    int cg = t & 15, ng = t >> 4;
    int c0 = cg * 4;
    float4 acc[4];
    #pragma unroll
    for (int i = 0; i < 4; i++) acc[i] = make_float4(0, 0, 0, 0);

    for (int kh = 0; kh < 2; kh++) {
        __syncthreads();   // xin ready (iter0) / previous half consumed (iter1)
        // stage W0 half (k-major, coalesced float4)
        {
            const float4* W04 = (const float4*)W0;
            float4* ws4 = (float4*)&ws[0][0];
            for (int i = t; i < 1536; i += 256)          // 96 rows x 16 float4
                ws4[i] = W04[(size_t)kh * 1536 + i];
        }
        // compute encoder outputs for this half: xs[n][kk], col = kh*96+kk
        for (int i = t; i < 6144; i += 256) {            // 64 nodes x 96 cols
            int n = i / 96, kk = i - n * 96;
            int col = kh * 96 + kk;
            float a;
            if (col < 64) {
                a = bf[col];
                #pragma unroll
                for (int k = 0; k < 8; k++) a = fmaf(xin[n][k], Wf[k * 64 + col], a);
            } else if (col < 128) {
                int c = col - 64;
                a = bw[c];
                #pragma unroll
                for (int k = 0; k < 12; k++) a = fmaf(xin[n][8 + k], Ww[k * 64 + c], a);
            } else {
                int c = col - 128;
                a = bt[c];
                #pragma unroll
                for (int k = 0; k < 10; k++) a = fmaf(xin[n][20 + k], Wt[k * 64 + c], a);
            }
            xs[n][kk] = fmaxf(a, 0.f);
        }
        __syncthreads();
        // register-blocked GEMM over this 96-half
        for (int k = 0; k < 96; k += 4) {
            float4 b0 = *(const float4*)&ws[k + 0][c0];
            float4 b1 = *(const float4*)&ws[k + 1][c0];
            float4 b2 = *(const float4*)&ws[k + 2][c0];
            float4 b3 = *(const float4*)&ws[k + 3][c0];
            #pragma unroll
            for (int i = 0; i < 4; i++) {
                float4 a = *(const float4*)&xs[ng * 4 + i][k];
                fma4(acc[i], a.x, b0); fma4(acc[i], a.y, b1);
                fma4(acc[i], a.z, b2); fma4(acc[i], a.w, b3);
            }
        }
    }
    float4* h4 = (float4*)h;
    #pragma unroll
    for (int i = 0; i < 4; i++) {
        int gn = n0 + ng * 4 + i;
        if (gn < NN) h4[(size_t)gn * 16 + cg] = acc[i];
    }
}

// ---------------- 64x64 matmul, register-blocked: h = x @ W ----------------
__global__ void __launch_bounds__(256) mm64_kernel(
    const float* __restrict__ x, const float* __restrict__ W, float* __restrict__ h) {
    __shared__ float xs[64][68];   // +4 pad: conflict-free, 16B-aligned b128
    __shared__ float ws[64][64];   // k-major: 2-way bank alias only (free)
    int t = threadIdx.x;
    int n0 = blockIdx.x * 64;
    {
        const float4* W4 = (const float4*)W;
        float4* ws4 = (float4*)&ws[0][0];
        for (int i = t; i < 1024; i += 256) ws4[i] = W4[i];
        const float4* x4 = (const float4*)x;
        for (int i = t; i < 1024; i += 256) {
            int n = i >> 4, q = i & 15;
            int gn = n0 + n;
            float4 v = make_float4(0, 0, 0, 0);
            if (gn < NN) v = x4[(size_t)gn * 16 + q];
            *(float4*)&xs[n][q * 4] = v;
        }
    }
    __syncthreads();
    int cg = t & 15, ng = t >> 4;
    int c0 = cg * 4;
    float4 acc[4];
    #pragma unroll
    for (int i = 0; i < 4; i++) acc[i] = make_float4(0, 0, 0, 0);
    for (int k = 0; k < 64; k += 4) {
        float4 b0 = *(const float4*)&ws[k + 0][c0];
        float4 b1 = *(const float4*)&ws[k + 1][c0];
        float4 b2 = *(const float4*)&ws[k + 2][c0];
        float4 b3 = *(const float4*)&ws[k + 3][c0];
        #pragma unroll
        for (int i = 0; i < 4; i++) {
            float4 a = *(const float4*)&xs[ng * 4 + i][k];
            fma4(acc[i], a.x, b0); fma4(acc[i], a.y, b1);
            fma4(acc[i], a.z, b2); fma4(acc[i], a.w, b3);
        }
    }
    float4* h4 = (float4*)h;
    #pragma unroll
    for (int i = 0; i < 4; i++) {
        int gn = n0 + ng * 4 + i;
        if (gn < NN) h4[(size_t)gn * 16 + cg] = acc[i];
    }
}

// ---------------- CSR gather + finalize (float4 row-gathers) ----------------
// wave per node; wave = 4 edge-slots (g) x 16 float4-lanes (q).
// One global_load_dwordx4 fetches 4 different edge rows simultaneously.
__global__ void __launch_bounds__(256) gather_kernel(
    const int2* __restrict__ colw, const int* __restrict__ rowptr,
    const float* __restrict__ dinv, const float* __restrict__ h,
    const float* __restrict__ bias, float* __restrict__ out) {
    int n = (blockIdx.x * blockDim.x + threadIdx.x) >> 6;
    int l = threadIdx.x & 63;
    if (n >= NN) return;
    int g = l >> 4;      // edge sub-slot 0..3
    int q = l & 15;      // float4 slot 0..15
    const float4* h4 = (const float4*)h;
    float4 acc = make_float4(0, 0, 0, 0);
    int r0 = rowptr[n], r1 = rowptr[n + 1];
    for (int base = r0; base < r1; base += 64) {
        int cnt = min(64, r1 - base);
        int2 p = make_int2(0, 0);            // w=0 for inactive slots
        if (l < cnt) p = colw[base + l];
        int steps = (cnt + 3) >> 2;
        for (int j = 0; j < steps; j++) {
            int e = j * 4 + g;               // edge slot this lane-group handles
            int s = __shfl(p.x, e);
            float w = __int_as_float(__shfl(p.y, e));
            float4 v = h4[(size_t)s * 16 + q];
            acc.x = fmaf(v.x, w, acc.x);
            acc.y = fmaf(v.y, w, acc.y);
            acc.z = fmaf(v.z, w, acc.z);
            acc.w = fmaf(v.w, w, acc.w);
        }
    }
    // reduce across the 4 edge sub-slots (lanes l, l^16, l^32, l^48)
    acc.x += __shfl_xor(acc.x, 16); acc.y += __shfl_xor(acc.y, 16);
    acc.z += __shfl_xor(acc.z, 16); acc.w += __shfl_xor(acc.w, 16);
    acc.x += __shfl_xor(acc.x, 32); acc.y += __shfl_xor(acc.y, 32);
    acc.z += __shfl_xor(acc.z, 32); acc.w += __shfl_xor(acc.w, 32);
    if (g == 0) {
        float dn = dinv[n];
        float4 hn = h4[(size_t)n * 16 + q];
        float4 b4 = ((const float4*)bias)[q];
        float4 r;
        r.x = fmaxf(fmaf(dn, acc.x + hn.x * dn, b4.x), 0.f);
        r.y = fmaxf(fmaf(dn, acc.y + hn.y * dn, b4.y), 0.f);
        r.z = fmaxf(fmaf(dn, acc.z + hn.z * dn, b4.z), 0.f);
        r.w = fmaxf(fmaf(dn, acc.w + hn.w * dn, b4.w), 0.f);
        ((float4*)out)[(size_t)n * 16 + q] = r;
    }
}

// ---------------- fused output MLP ----------------
__global__ void __launch_bounds__(256) mlp_kernel(
    const float* __restrict__ x, const float* __restrict__ w1, const float* __restrict__ b1,
    const float* __restrict__ w2, const float* __restrict__ b2, float* __restrict__ out) {
    int t = threadIdx.x;
    int nl = t >> 5, j = t & 31;
    int n = blockIdx.x * 8 + nl;
    float acc = b1[j];
    if (n < NN) {
        #pragma unroll
        for (int k = 0; k < 64; k++) acc = fmaf(x[n * 64 + k], w1[k * 32 + j], acc);
    }
    float hj = fmaxf(acc, 0.f) * w2[j];
    #pragma unroll
    for (int off = 16; off; off >>= 1) hj += __shfl_down(hj, off, 32);
    if (j == 0 && n < NN) out[n] = hj + b2[0];
}

extern "C" void kernel_launch(void* const* d_in, const int* in_sizes, int n_in,
                              void* d_out, int out_size, void* d_ws, size_t ws_size,
                              hipStream_t stream) {
    const float* xf = (const float*)d_in[0];
    const float* xw = (const float*)d_in[1];
    const float* xt = (const float*)d_in[2];
    const int*   ei = (const int*)d_in[3];
    const int*   src = ei;
    const int*   dst = ei + NE;
    const float* Wf = (const float*)d_in[4];
    const float* bf = (const float*)d_in[5];
    const float* Ww = (const float*)d_in[6];
    const float* bw = (const float*)d_in[7];
    const float* Wt = (const float*)d_in[8];
    const float* bt = (const float*)d_in[9];
    const float* W0 = (const float*)d_in[10];
    const float* b0 = (const float*)d_in[11];
    const float* W1 = (const float*)d_in[12];
    const float* b1 = (const float*)d_in[13];
    const float* W2 = (const float*)d_in[14];
    const float* b2 = (const float*)d_in[15];
    const float* ow1 = (const float*)d_in[16];
    const float* ob1 = (const float*)d_in[17];
    const float* ow2 = (const float*)d_in[18];
    const float* ob2 = (const float*)d_in[19];
    float* out = (float*)d_out;

    // workspace layout (~104 MB)
    char* w = (char*)d_ws;
    float* h      = (float*)w;  w += (size_t)NN * 64 * 4;    // 25.6 MB
    float* agg    = (float*)w;  w += (size_t)NN * 64 * 4;    // 25.6 MB
    int2*  colw   = (int2*)w;   w += (size_t)NE * 8;         // 25.6 MB
    float* dinv   = (float*)w;  w += (size_t)NN * 4;
    int*   deg    = (int*)w;    w += (size_t)NN * 4;
    int*   cursor = (int*)w;    w += (size_t)NN * 4;
    int*   rowptr = (int*)w;    w += (size_t)(NN + 1) * 4;
    int*   bsum   = (int*)w;    w += (size_t)NBLK * 4;
    int*   boff   = (int*)w;    w += (size_t)NBLK * 4;

    // ---- CSR build (once; reused by all 3 layers) ----
    hipMemsetAsync(deg, 0, (size_t)NN * 4, stream);
    hipMemsetAsync(cursor, 0, (size_t)NN * 4, stream);
    deg_kernel<<<(NE + 255) / 256, 256, 0, stream>>>(dst, deg);
    dinv_kernel<<<(NN + 255) / 256, 256, 0, stream>>>(deg, dinv);
    block_sum_kernel<<<NBLK, 256, 0, stream>>>(deg, bsum);
    scan_bsum_kernel<<<1, 64, 0, stream>>>(bsum, boff, rowptr);
    scan_fill_kernel<<<NBLK, 256, 0, stream>>>(deg, boff, rowptr);
    fill_csr_kernel<<<(NE + 255) / 256, 256, 0, stream>>>(src, dst, rowptr, cursor, dinv, colw);

    // ---- layer 0: fused encoders + matmul, then gather+finalize ----
    encmm0_kernel<<<(NN + 63) / 64, 256, 0, stream>>>(xf, xw, xt, Wf, bf, Ww, bw, Wt, bt, W0, h);
    gather_kernel<<<(NN * 64 + 255) / 256, 256, 0, stream>>>(colw, rowptr, dinv, h, b0, agg);

    // ---- layer 1 ----
    mm64_kernel<<<(NN + 63) / 64, 256, 0, stream>>>(agg, W1, h);
    gather_kernel<<<(NN * 64 + 255) / 256, 256, 0, stream>>>(colw, rowptr, dinv, h, b1, agg);

    // ---- layer 2 ----
    mm64_kernel<<<(NN + 63) / 64, 256, 0, stream>>>(agg, W2, h);
    gather_kernel<<<(NN * 64 + 255) / 256, 256, 0, stream>>>(colw, rowptr, dinv, h, b2, agg);

    // ---- output MLP ----
    mlp_kernel<<<(NN + 7) / 8, 256, 0, stream>>>(agg, ow1, ob1, ow2, ob2, out);
}

// Round 4
// 898.067 us; speedup vs baseline: 2.9489x; 1.0357x over previous
//
#include <hip/hip_runtime.h>

#define NN 100000
#define NE 3200000
#define HD 64
#define SCAN_CHUNK 1024
#define NBLK ((NN + SCAN_CHUNK - 1) / SCAN_CHUNK)   // 98
#define NRANGE 8
#define RANGE_W (NN / NRANGE)                       // 12500

__device__ __forceinline__ void fma4(float4& a, float s, const float4& b) {
    a.x = fmaf(s, b.x, a.x); a.y = fmaf(s, b.y, a.y);
    a.z = fmaf(s, b.z, a.z); a.w = fmaf(s, b.w, a.w);
}

// ---------------- degree histogram ----------------
__global__ void deg_kernel(const int* __restrict__ dst, int* __restrict__ deg) {
    int e = blockIdx.x * blockDim.x + threadIdx.x;
    if (e < NE) atomicAdd(&deg[dst[e]], 1);
}

__global__ void dinv_kernel(const int* __restrict__ deg, float* __restrict__ dinv) {
    int i = blockIdx.x * blockDim.x + threadIdx.x;
    if (i < NN) dinv[i] = 1.0f / sqrtf((float)(deg[i] + 1)); // +1 self-loop
}

// ---------------- prefix scan (3 kernels) ----------------
__global__ void block_sum_kernel(const int* __restrict__ deg, int* __restrict__ bsum) {
    __shared__ int red[256];
    int b = blockIdx.x, t = threadIdx.x;
    int base = b * SCAN_CHUNK + t * 4;
    int s = 0;
    #pragma unroll
    for (int i = 0; i < 4; i++) { int g = base + i; if (g < NN) s += deg[g]; }
    red[t] = s; __syncthreads();
    for (int off = 128; off > 0; off >>= 1) {
        if (t < off) red[t] += red[t + off];
        __syncthreads();
    }
    if (t == 0) bsum[b] = red[0];
}

__global__ void scan_bsum_kernel(const int* __restrict__ bsum, int* __restrict__ boff,
                                 int* __restrict__ rowptr) {
    if (threadIdx.x == 0) {
        int off = 0;
        for (int i = 0; i < NBLK; i++) { boff[i] = off; off += bsum[i]; }
        rowptr[NN] = off;   // == NE
    }
}

__global__ void scan_fill_kernel(const int* __restrict__ deg, const int* __restrict__ boff,
                                 int* __restrict__ rowptr) {
    __shared__ int part[256];
    int b = blockIdx.x, t = threadIdx.x;
    int base = b * SCAN_CHUNK + t * 4;
    int v[4];
    #pragma unroll
    for (int i = 0; i < 4; i++) { int g = base + i; v[i] = (g < NN) ? deg[g] : 0; }
    int tsum = v[0] + v[1] + v[2] + v[3];
    part[t] = tsum; __syncthreads();
    for (int off = 1; off < 256; off <<= 1) {
        int x = (t >= off) ? part[t - off] : 0;
        __syncthreads();
        part[t] += x;
        __syncthreads();
    }
    int o = boff[b] + part[t] - tsum;   // exclusive prefix for this thread
    #pragma unroll
    for (int i = 0; i < 4; i++) {
        int g = base + i;
        if (g < NN) rowptr[g] = o;
        o += v[i];
    }
}

// ---------------- CSR fill, XCD-partitioned by dst range ----------------
// blockIdx % 8 -> XCD (dispatch heuristic). Each XCD owns a contiguous dst
// range (~3.2 MB of colw, fits its 4 MiB L2), so colw lines are dirtied by
// ONE XCD only -> writeback ~25.6 MB instead of 8x-amplified 205 MB.
// Every block streams the whole (int4-vectorized) edge list; the 25.6 MB
// src/dst stream is L3-resident so the 8x re-read is cheap.
__global__ void __launch_bounds__(256) fill_csr_kernel(
    const int* __restrict__ src, const int* __restrict__ dst,
    const int* __restrict__ rowptr, int* __restrict__ cursor,
    const float* __restrict__ dinv, int2* __restrict__ colw) {
    int r  = blockIdx.x & 7;          // dst range / target XCD
    int bi = blockIdx.x >> 3;         // block index within range
    int nb = gridDim.x >> 3;          // blocks per range
    int lo = r * RANGE_W, hi = lo + RANGE_W;
    const int4* dst4 = (const int4*)dst;
    const int4* src4 = (const int4*)src;
    const int NE4 = NE / 4;
    for (int base = bi * 256; base < NE4; base += nb * 256) {
        int i = base + threadIdx.x;
        if (i >= NE4) break;
        int4 d4 = dst4[i];
        int4 s4 = src4[i];
        #pragma unroll
        for (int k = 0; k < 4; k++) {
            int d = (k == 0) ? d4.x : (k == 1) ? d4.y : (k == 2) ? d4.z : d4.w;
            if (d >= lo && d < hi) {
                int s = (k == 0) ? s4.x : (k == 1) ? s4.y : (k == 2) ? s4.z : s4.w;
                int slot = atomicAdd(&cursor[d], 1);
                int2 p;
                p.x = s;
                p.y = __float_as_int(dinv[s]);
                colw[rowptr[d] + slot] = p;
            }
        }
    }
}

// ---------------- fused modality encoders + GCN layer-0 matmul ----------------
__global__ void __launch_bounds__(256) encmm0_kernel(
    const float* __restrict__ xf, const float* __restrict__ xw, const float* __restrict__ xt,
    const float* __restrict__ Wf, const float* __restrict__ bf,
    const float* __restrict__ Ww, const float* __restrict__ bw,
    const float* __restrict__ Wt, const float* __restrict__ bt,
    const float* __restrict__ W0, float* __restrict__ h) {
    __shared__ float xin[64][32];    // fire[0..7], wea[8..19], ter[20..29]
    __shared__ float xs[64][100];    // encoder outputs for current 96-half (+4 pad)
    __shared__ float ws[96][64];     // W0 rows for current half
    int t = threadIdx.x;
    int n0 = blockIdx.x * 64;

    {
        const float4* xf4 = (const float4*)xf;
        for (int i = t; i < 128; i += 256) {
            int n = i >> 1, q = i & 1;
            int gn = n0 + n;
            float4 v = make_float4(0, 0, 0, 0);
            if (gn < NN) v = xf4[(size_t)gn * 2 + q];
            *(float4*)&xin[n][q * 4] = v;
        }
        const float4* xw4 = (const float4*)xw;
        for (int i = t; i < 192; i += 256) {
            int n = i / 3, q = i - n * 3;
            int gn = n0 + n;
            float4 v = make_float4(0, 0, 0, 0);
            if (gn < NN) v = xw4[(size_t)gn * 3 + q];
            *(float4*)&xin[n][8 + q * 4] = v;
        }
        const float2* xt2 = (const float2*)xt;
        for (int i = t; i < 320; i += 256) {
            int n = i / 5, q = i - n * 5;
            int gn = n0 + n;
            float2 v = make_float2(0, 0);
            if (gn < NN) v = xt2[(size_t)gn * 5 + q];
            *(float2*)&xin[n][20 + q * 2] = v;
        }
    }

    int cg = t & 15, ng = t >> 4;
    int c0 = cg * 4;
    float4 acc[4];
    #pragma unroll
    for (int i = 0; i < 4; i++) acc[i] = make_float4(0, 0, 0, 0);

    for (int kh = 0; kh < 2; kh++) {
        __syncthreads();
        {
            const float4* W04 = (const float4*)W0;
            float4* ws4 = (float4*)&ws[0][0];
            for (int i = t; i < 1536; i += 256)
                ws4[i] = W04[(size_t)kh * 1536 + i];
        }
        for (int i = t; i < 6144; i += 256) {
            int n = i / 96, kk = i - n * 96;
            int col = kh * 96 + kk;
            float a;
            if (col < 64) {
                a = bf[col];
                #pragma unroll
                for (int k = 0; k < 8; k++) a = fmaf(xin[n][k], Wf[k * 64 + col], a);
            } else if (col < 128) {
                int c = col - 64;
                a = bw[c];
                #pragma unroll
                for (int k = 0; k < 12; k++) a = fmaf(xin[n][8 + k], Ww[k * 64 + c], a);
            } else {
                int c = col - 128;
                a = bt[c];
                #pragma unroll
                for (int k = 0; k < 10; k++) a = fmaf(xin[n][20 + k], Wt[k * 64 + c], a);
            }
            xs[n][kk] = fmaxf(a, 0.f);
        }
        __syncthreads();
        for (int k = 0; k < 96; k += 4) {
            float4 b0 = *(const float4*)&ws[k + 0][c0];
            float4 b1 = *(const float4*)&ws[k + 1][c0];
            float4 b2 = *(const float4*)&ws[k + 2][c0];
            float4 b3 = *(const float4*)&ws[k + 3][c0];
            #pragma unroll
            for (int i = 0; i < 4; i++) {
                float4 a = *(const float4*)&xs[ng * 4 + i][k];
                fma4(acc[i], a.x, b0); fma4(acc[i], a.y, b1);
                fma4(acc[i], a.z, b2); fma4(acc[i], a.w, b3);
            }
        }
    }
    float4* h4 = (float4*)h;
    #pragma unroll
    for (int i = 0; i < 4; i++) {
        int gn = n0 + ng * 4 + i;
        if (gn < NN) h4[(size_t)gn * 16 + cg] = acc[i];
    }
}

// ---------------- 64x64 matmul, register-blocked: h = x @ W ----------------
__global__ void __launch_bounds__(256) mm64_kernel(
    const float* __restrict__ x, const float* __restrict__ W, float* __restrict__ h) {
    __shared__ float xs[64][68];
    __shared__ float ws[64][64];
    int t = threadIdx.x;
    int n0 = blockIdx.x * 64;
    {
        const float4* W4 = (const float4*)W;
        float4* ws4 = (float4*)&ws[0][0];
        for (int i = t; i < 1024; i += 256) ws4[i] = W4[i];
        const float4* x4 = (const float4*)x;
        for (int i = t; i < 1024; i += 256) {
            int n = i >> 4, q = i & 15;
            int gn = n0 + n;
            float4 v = make_float4(0, 0, 0, 0);
            if (gn < NN) v = x4[(size_t)gn * 16 + q];
            *(float4*)&xs[n][q * 4] = v;
        }
    }
    __syncthreads();
    int cg = t & 15, ng = t >> 4;
    int c0 = cg * 4;
    float4 acc[4];
    #pragma unroll
    for (int i = 0; i < 4; i++) acc[i] = make_float4(0, 0, 0, 0);
    for (int k = 0; k < 64; k += 4) {
        float4 b0 = *(const float4*)&ws[k + 0][c0];
        float4 b1 = *(const float4*)&ws[k + 1][c0];
        float4 b2 = *(const float4*)&ws[k + 2][c0];
        float4 b3 = *(const float4*)&ws[k + 3][c0];
        #pragma unroll
        for (int i = 0; i < 4; i++) {
            float4 a = *(const float4*)&xs[ng * 4 + i][k];
            fma4(acc[i], a.x, b0); fma4(acc[i], a.y, b1);
            fma4(acc[i], a.z, b2); fma4(acc[i], a.w, b3);
        }
    }
    float4* h4 = (float4*)h;
    #pragma unroll
    for (int i = 0; i < 4; i++) {
        int gn = n0 + ng * 4 + i;
        if (gn < NN) h4[(size_t)gn * 16 + cg] = acc[i];
    }
}

// ---------------- CSR gather + finalize (float4 row-gathers, 4-deep MLP) ----
// wave per node; wave = 4 edge-slots (g) x 16 float4-lanes (q).
// Inner loop unrolled 4x so each lane keeps 4 independent dwordx4 loads
// in flight (the dynamic-count loop otherwise serializes one load/iter).
__global__ void __launch_bounds__(256) gather_kernel(
    const int2* __restrict__ colw, const int* __restrict__ rowptr,
    const float* __restrict__ dinv, const float* __restrict__ h,
    const float* __restrict__ bias, float* __restrict__ out) {
    int n = (blockIdx.x * blockDim.x + threadIdx.x) >> 6;
    int l = threadIdx.x & 63;
    if (n >= NN) return;
    int g = l >> 4;      // edge sub-slot 0..3
    int q = l & 15;      // float4 slot 0..15
    const float4* h4 = (const float4*)h;
    float4 acc = make_float4(0, 0, 0, 0);
    int r0 = rowptr[n], r1 = rowptr[n + 1];
    for (int base = r0; base < r1; base += 64) {
        int cnt = min(64, r1 - base);
        int2 p = make_int2(0, 0);            // w=0 for inactive slots
        if (l < cnt) p = colw[base + l];
        int steps = (cnt + 3) >> 2;
        int j = 0;
        for (; j + 4 <= steps; j += 4) {
            int e0 = (j + 0) * 4 + g, e1 = (j + 1) * 4 + g;
            int e2 = (j + 2) * 4 + g, e3 = (j + 3) * 4 + g;
            int s0 = __shfl(p.x, e0); float w0 = __int_as_float(__shfl(p.y, e0));
            int s1 = __shfl(p.x, e1); float w1 = __int_as_float(__shfl(p.y, e1));
            int s2 = __shfl(p.x, e2); float w2 = __int_as_float(__shfl(p.y, e2));
            int s3 = __shfl(p.x, e3); float w3 = __int_as_float(__shfl(p.y, e3));
            float4 v0 = h4[(size_t)s0 * 16 + q];
            float4 v1 = h4[(size_t)s1 * 16 + q];
            float4 v2 = h4[(size_t)s2 * 16 + q];
            float4 v3 = h4[(size_t)s3 * 16 + q];
            fma4(acc, w0, v0); fma4(acc, w1, v1);
            fma4(acc, w2, v2); fma4(acc, w3, v3);
        }
        for (; j < steps; j++) {
            int e = j * 4 + g;
            int s = __shfl(p.x, e);
            float w = __int_as_float(__shfl(p.y, e));
            float4 v = h4[(size_t)s * 16 + q];
            fma4(acc, w, v);
        }
    }
    acc.x += __shfl_xor(acc.x, 16); acc.y += __shfl_xor(acc.y, 16);
    acc.z += __shfl_xor(acc.z, 16); acc.w += __shfl_xor(acc.w, 16);
    acc.x += __shfl_xor(acc.x, 32); acc.y += __shfl_xor(acc.y, 32);
    acc.z += __shfl_xor(acc.z, 32); acc.w += __shfl_xor(acc.w, 32);
    if (g == 0) {
        float dn = dinv[n];
        float4 hn = h4[(size_t)n * 16 + q];
        float4 b4 = ((const float4*)bias)[q];
        float4 r;
        r.x = fmaxf(fmaf(dn, acc.x + hn.x * dn, b4.x), 0.f);
        r.y = fmaxf(fmaf(dn, acc.y + hn.y * dn, b4.y), 0.f);
        r.z = fmaxf(fmaf(dn, acc.z + hn.z * dn, b4.z), 0.f);
        r.w = fmaxf(fmaf(dn, acc.w + hn.w * dn, b4.w), 0.f);
        ((float4*)out)[(size_t)n * 16 + q] = r;
    }
}

// ---------------- fused output MLP ----------------
__global__ void __launch_bounds__(256) mlp_kernel(
    const float* __restrict__ x, const float* __restrict__ w1, const float* __restrict__ b1,
    const float* __restrict__ w2, const float* __restrict__ b2, float* __restrict__ out) {
    int t = threadIdx.x;
    int nl = t >> 5, j = t & 31;
    int n = blockIdx.x * 8 + nl;
    float acc = b1[j];
    if (n < NN) {
        #pragma unroll
        for (int k = 0; k < 64; k++) acc = fmaf(x[n * 64 + k], w1[k * 32 + j], acc);
    }
    float hj = fmaxf(acc, 0.f) * w2[j];
    #pragma unroll
    for (int off = 16; off; off >>= 1) hj += __shfl_down(hj, off, 32);
    if (j == 0 && n < NN) out[n] = hj + b2[0];
}

extern "C" void kernel_launch(void* const* d_in, const int* in_sizes, int n_in,
                              void* d_out, int out_size, void* d_ws, size_t ws_size,
                              hipStream_t stream) {
    const float* xf = (const float*)d_in[0];
    const float* xw = (const float*)d_in[1];
    const float* xt = (const float*)d_in[2];
    const int*   ei = (const int*)d_in[3];
    const int*   src = ei;
    const int*   dst = ei + NE;
    const float* Wf = (const float*)d_in[4];
    const float* bf = (const float*)d_in[5];
    const float* Ww = (const float*)d_in[6];
    const float* bw = (const float*)d_in[7];
    const float* Wt = (const float*)d_in[8];
    const float* bt = (const float*)d_in[9];
    const float* W0 = (const float*)d_in[10];
    const float* b0 = (const float*)d_in[11];
    const float* W1 = (const float*)d_in[12];
    const float* b1 = (const float*)d_in[13];
    const float* W2 = (const float*)d_in[14];
    const float* b2 = (const float*)d_in[15];
    const float* ow1 = (const float*)d_in[16];
    const float* ob1 = (const float*)d_in[17];
    const float* ow2 = (const float*)d_in[18];
    const float* ob2 = (const float*)d_in[19];
    float* out = (float*)d_out;

    // workspace layout (~104 MB)
    char* w = (char*)d_ws;
    float* h      = (float*)w;  w += (size_t)NN * 64 * 4;    // 25.6 MB
    float* agg    = (float*)w;  w += (size_t)NN * 64 * 4;    // 25.6 MB
    int2*  colw   = (int2*)w;   w += (size_t)NE * 8;         // 25.6 MB
    float* dinv   = (float*)w;  w += (size_t)NN * 4;
    int*   deg    = (int*)w;    w += (size_t)NN * 4;
    int*   cursor = (int*)w;    w += (size_t)NN * 4;
    int*   rowptr = (int*)w;    w += (size_t)(NN + 1) * 4;
    int*   bsum   = (int*)w;    w += (size_t)NBLK * 4;
    int*   boff   = (int*)w;    w += (size_t)NBLK * 4;

    // ---- CSR build (once; reused by all 3 layers) ----
    hipMemsetAsync(deg, 0, (size_t)NN * 4, stream);
    hipMemsetAsync(cursor, 0, (size_t)NN * 4, stream);
    deg_kernel<<<(NE + 255) / 256, 256, 0, stream>>>(dst, deg);
    dinv_kernel<<<(NN + 255) / 256, 256, 0, stream>>>(deg, dinv);
    block_sum_kernel<<<NBLK, 256, 0, stream>>>(deg, bsum);
    scan_bsum_kernel<<<1, 64, 0, stream>>>(bsum, boff, rowptr);
    scan_fill_kernel<<<NBLK, 256, 0, stream>>>(deg, boff, rowptr);
    fill_csr_kernel<<<1024, 256, 0, stream>>>(src, dst, rowptr, cursor, dinv, colw);

    // ---- layer 0: fused encoders + matmul, then gather+finalize ----
    encmm0_kernel<<<(NN + 63) / 64, 256, 0, stream>>>(xf, xw, xt, Wf, bf, Ww, bw, Wt, bt, W0, h);
    gather_kernel<<<(NN * 64 + 255) / 256, 256, 0, stream>>>(colw, rowptr, dinv, h, b0, agg);

    // ---- layer 1 ----
    mm64_kernel<<<(NN + 63) / 64, 256, 0, stream>>>(agg, W1, h);
    gather_kernel<<<(NN * 64 + 255) / 256, 256, 0, stream>>>(colw, rowptr, dinv, h, b1, agg);

    // ---- layer 2 ----
    mm64_kernel<<<(NN + 63) / 64, 256, 0, stream>>>(agg, W2, h);
    gather_kernel<<<(NN * 64 + 255) / 256, 256, 0, stream>>>(colw, rowptr, dinv, h, b2, agg);

    // ---- output MLP ----
    mlp_kernel<<<(NN + 7) / 8, 256, 0, stream>>>(agg, ow1, ob1, ow2, ob2, out);
}